// Round 16
// baseline (30.810 us; speedup 1.0000x reference)
//
#include <hip/hip_runtime.h>

// BilateralFilter fp32 I/O, 8 images 512x512, 3x3, sigma=0.8.
// v16: LOW-REGISTER / HIGH-OCCUPANCY regime (R1's winning occupancy pattern
// + v11's packed-fp16 math). 1 row x 4 px per thread; the 3 window rows are
// processed in a no-unroll loop so only ONE 25-reg fp16 window is live at a
// time. No in-thread prefetch - 6-7 resident waves/SIMD hide latency (TLP).
// Packed-fp16, poly-exp (zero transcendentals), exact zero-pad semantics.

typedef _Float16 h2 __attribute__((ext_vector_type(2)));

constexpr int HH = 512, WW = 512, HW = HH * WW;

__device__ __forceinline__ h2 H2c(float v) { return h2{(_Float16)v, (_Float16)v}; }
__device__ __forceinline__ h2 pkrtz(float a, float b) {
    return __builtin_bit_cast(h2, __builtin_amdgcn_cvt_pkrtz(a, b));
}

// w(s)=e^(-0.78125*s), s=d^2 in [0,1]; deg-4 Taylor at s=0.5 (rel err ~5e-5)
__device__ __forceinline__ h2 wpoly(h2 d) {
    h2 v = d * d + H2c(-0.5f);
    h2 w = H2c(-0.0537742f) + v * H2c(0.0105029f);
    w = H2c(0.206495f) + v * w;
    w = H2c(-0.528620f) + v * w;
    w = H2c(0.676634f) + v * w;
    return w;
}

#define WS0f 0.2724967f
#define WS1f 0.1247577f
#define WS2f 0.0571180f

struct RW  { h2 d[5], m[5], x[5], y[5], z[5]; };   // 25 VGPR, one at a time
struct Acc { h2 swd, swc, st, s0, s1, s2; };

__global__ __launch_bounds__(256) void bilateral_v16(
    const float* __restrict__ depth,
    const float* __restrict__ color,
    const float* __restrict__ mask,
    float* __restrict__ out)
{
    const int lane = threadIdx.x & 63;
    const int wg   = blockIdx.x * 4 + (threadIdx.x >> 6);
    const int n    = wg >> 10;              // image 0..7
    const int rem  = wg & 1023;
    const int r    = rem >> 1;              // output row 0..511
    const int half = rem & 1;
    const int c0   = half * 256 + lane * 4;

    const float* dptr = depth + (size_t)n * HW;
    const float* mptr = mask  + (size_t)n * HW;
    const float* xptr = color + (size_t)n * 3 * HW;
    const float* yptr = xptr + HW;
    const float* zptr = xptr + 2 * HW;

    const bool hasL = (c0 > 0);
    const bool hasR = (c0 < WW - 4);
    const int  colL = hasL ? c0 - 2 : c0;   // aligned float2, clamped
    const int  colR = hasR ? c0 + 4 : c0;

// One plane of one row: 3 loads -> 5 packs (staging = 8 fp32 regs, reused).
#define LOADPLANE(dst, base, o) do {                                         \
    const float4 _q = *reinterpret_cast<const float4*>((base) + (o) + c0);   \
    const float2 _l = *reinterpret_cast<const float2*>((base) + (o) + colL); \
    const float2 _r = *reinterpret_cast<const float2*>((base) + (o) + colR); \
    dst[0] = pkrtz(hasL ? _l.y : 0.0f, _q.x);                                \
    dst[1] = pkrtz(_q.x, _q.y);                                              \
    dst[2] = pkrtz(_q.y, _q.z);                                              \
    dst[3] = pkrtz(_q.z, _q.w);                                              \
    dst[4] = pkrtz(_q.w, hasR ? _r.x : 0.0f);                                \
} while (0)

#define TAP(S_, pi, cD, cX, cY, cZ, WSC, A_) do {                            \
    const h2 _wd = wpoly(S_.d[pi] - (cD));                                   \
    const h2 _w0 = wpoly(S_.x[pi] - (cX));                                   \
    const h2 _w1 = wpoly(S_.y[pi] - (cY));                                   \
    const h2 _w2 = wpoly(S_.z[pi] - (cZ));                                   \
    const h2 _wc = _w0 + _w1 + _w2;                                          \
    const h2 _t  = (_wd * _wc) * ((WSC) * S_.m[pi]);                         \
    A_.swd += _wd; A_.swc += _wc; A_.st += _t;                               \
    A_.s0 += _t * S_.x[pi]; A_.s1 += _t * S_.y[pi]; A_.s2 += _t * S_.z[pi];  \
} while (0)

    // Preload the 4 center packs of row r (d, x, y, z planes only).
    h2 cd0, cd1, cx0, cx1, cy0, cy1, cz0, cz1;
    {
        const int o = r * WW + c0;
        const float4 qd = *reinterpret_cast<const float4*>(dptr + o);
        const float4 qx = *reinterpret_cast<const float4*>(xptr + o);
        const float4 qy = *reinterpret_cast<const float4*>(yptr + o);
        const float4 qz = *reinterpret_cast<const float4*>(zptr + o);
        cd0 = pkrtz(qd.x, qd.y); cd1 = pkrtz(qd.z, qd.w);
        cx0 = pkrtz(qx.x, qx.y); cx1 = pkrtz(qx.z, qx.w);
        cy0 = pkrtz(qy.x, qy.y); cy1 = pkrtz(qy.z, qy.w);
        cz0 = pkrtz(qz.x, qz.y); cz1 = pkrtz(qz.z, qz.w);
    }

    Acc a0{}, a1{};

    #pragma unroll 1
    for (int dr = -1; dr <= 1; ++dr) {
        const int rr = r + dr;
        const bool valid = ((unsigned)rr < (unsigned)HH);   // wave-uniform
        RW W;
        if (valid) {
            const int o = rr * WW;
            LOADPLANE(W.d, dptr, o);
            LOADPLANE(W.m, mptr, o);
            LOADPLANE(W.x, xptr, o);
            LOADPLANE(W.y, yptr, o);
            LOADPLANE(W.z, zptr, o);
        } else {
            #pragma unroll
            for (int j = 0; j < 5; ++j) {
                W.d[j] = h2{0,0}; W.m[j] = h2{0,0}; W.x[j] = h2{0,0};
                W.y[j] = h2{0,0}; W.z[j] = h2{0,0};
            }
        }
        // Spatial weights for this row: dr==0 -> (WS0 mid, WS1 side),
        // else (WS1 mid, WS2 side). Center tap goes through the same poly
        // path (wpoly(0) = 1 +- 5e-5; absorbed by the normalization).
        const h2 wsM = (dr == 0) ? H2c(WS0f) : H2c(WS1f);
        const h2 wsS = (dr == 0) ? H2c(WS1f) : H2c(WS2f);

        TAP(W, 0, cd0, cx0, cy0, cz0, wsS, a0);
        TAP(W, 1, cd0, cx0, cy0, cz0, wsM, a0);
        TAP(W, 2, cd0, cx0, cy0, cz0, wsS, a0);
        TAP(W, 2, cd1, cx1, cy1, cz1, wsS, a1);
        TAP(W, 3, cd1, cx1, cy1, cz1, wsM, a1);
        TAP(W, 4, cd1, cx1, cy1, cz1, wsS, a1);
    }

    // fp32 epilogue: out = S / (St + 9e-7*Swd*Swc)
    float o0[4], o1[4], o2[4];
#define EPI(A_, i0, i1) do {                                                 \
    {                                                                        \
        const float g   = (float)A_.st[0]                                    \
                        + 9e-7f * (float)A_.swd[0] * (float)A_.swc[0];       \
        const float inv = __builtin_amdgcn_rcpf(g);                          \
        o0[i0] = (float)A_.s0[0] * inv;                                      \
        o1[i0] = (float)A_.s1[0] * inv;                                      \
        o2[i0] = (float)A_.s2[0] * inv;                                      \
    }                                                                        \
    {                                                                        \
        const float g   = (float)A_.st[1]                                    \
                        + 9e-7f * (float)A_.swd[1] * (float)A_.swc[1];       \
        const float inv = __builtin_amdgcn_rcpf(g);                          \
        o0[i1] = (float)A_.s0[1] * inv;                                      \
        o1[i1] = (float)A_.s1[1] * inv;                                      \
        o2[i1] = (float)A_.s2[1] * inv;                                      \
    }                                                                        \
} while (0)

    EPI(a0, 0, 1);
    EPI(a1, 2, 3);

    float* po = out + (size_t)n * 3 * HW + r * WW + c0;
    *reinterpret_cast<float4*>(po)          = make_float4(o0[0], o0[1], o0[2], o0[3]);
    *reinterpret_cast<float4*>(po + HW)     = make_float4(o1[0], o1[1], o1[2], o1[3]);
    *reinterpret_cast<float4*>(po + 2 * HW) = make_float4(o2[0], o2[1], o2[2], o2[3]);
}

extern "C" void kernel_launch(void* const* d_in, const int* in_sizes, int n_in,
                              void* d_out, int out_size, void* d_ws, size_t ws_size,
                              hipStream_t stream) {
    const float* depth = (const float*)d_in[0];
    const float* color = (const float*)d_in[1];
    const float* mask  = (const float*)d_in[2];
    float* out = (float*)d_out;

    // 8 images * 512 rows * 2 halves = 8192 waves; 4 waves/block
    bilateral_v16<<<2048, 256, 0, stream>>>(depth, color, mask, out);
}

// Round 17
// 24.381 us; speedup vs baseline: 1.2637x; 1.2637x over previous
//
#include <hip/hip_runtime.h>

// BilateralFilter fp32 I/O, 8 images 512x512, 3x3, sigma=0.8.
// FINAL = v11 (best of 11 structural variants, 24.1 us).
// Packed-fp16 compute (2 px per v_pk_* instruction), weight exp replaced by
// degree-4 polynomial of s = diff^2 (w = e^(-0.78125*s), s in [0,1]).
// Zero transcendentals. 2 rows x 4 cols/thread, fp16 accum, fp32 epilogue.
//
// Session conclusions (why this is the floor):
//  - time ~= 18 us latency-spread memory term (5-stream stencil, cold L2/L3
//    each replay) + ~6 us packed-fp16 issue. Memory term invariant to
//    occupancy 2->7 waves/SIMD, prefetch, XCD swizzle, LDS staging, and
//    fetch-redundancy elimination (v12).
//  - scratch-spill fingerprint: WRITE_SIZE >> 24.6 MB (v3/v4/v8).
//  - __launch_bounds__ min-waves arg caps VGPR at 256/arg on this toolchain.

typedef _Float16 h2 __attribute__((ext_vector_type(2)));

constexpr int HH = 512, WW = 512, HW = HH * WW;

__device__ __forceinline__ h2 H2c(float v) { return h2{(_Float16)v, (_Float16)v}; }
__device__ __forceinline__ h2 pkrtz(float a, float b) {
    return __builtin_bit_cast(h2, __builtin_amdgcn_cvt_pkrtz(a, b));
}

// w(s) = e^(-0.78125*s), s in [0,1]; deg-4 Taylor at s=0.5 (rel err ~5e-5).
__device__ __forceinline__ h2 wpoly(h2 d) {
    h2 v = d * d + H2c(-0.5f);
    h2 w = H2c(-0.0537742f) + v * H2c(0.0105029f);
    w = H2c(0.206495f) + v * w;
    w = H2c(-0.528620f) + v * w;
    w = H2c(0.676634f) + v * w;
    return w;
}

#define WS0f 0.2724967f
#define WS1f 0.1247577f
#define WS2f 0.0571180f

struct RW {
    h2 d[5], m[5], x[5], y[5], z[5];
};
struct Acc { h2 swd, swc, st, s0, s1, s2; };

__global__ __launch_bounds__(256) void bilateral_v11(
    const float* __restrict__ depth,
    const float* __restrict__ color,
    const float* __restrict__ mask,
    float* __restrict__ out)
{
    const int lane = threadIdx.x & 63;
    const int wg   = blockIdx.x * 4 + (threadIdx.x >> 6);
    const int n    = wg >> 9;
    const int rem  = wg & 511;
    const int hp   = rem >> 1;              // row-pair 0..255
    const int half = rem & 1;
    const int rA   = hp * 2;
    const int c0   = half * 256 + lane * 4;

    const float* dptr = depth + (size_t)n * HW;
    const float* mptr = mask  + (size_t)n * HW;
    const float* xptr = color + (size_t)n * 3 * HW;
    const float* yptr = xptr + HW;
    const float* zptr = xptr + 2 * HW;

    const bool hasL = (c0 > 0);
    const bool hasR = (c0 < WW - 4);
    const int  colL = hasL ? c0 - 2 : c0;   // aligned float2, clamped
    const int  colR = hasR ? c0 + 4 : c0;

#define LOADCVT(P_, base, off) do {                                          \
    const float4 _q = *reinterpret_cast<const float4*>((base) + (off) + c0); \
    const float2 _l = *reinterpret_cast<const float2*>((base) + (off) + colL); \
    const float2 _r = *reinterpret_cast<const float2*>((base) + (off) + colR); \
    const float _eL = hasL ? _l.y : 0.0f;                                    \
    const float _eR = hasR ? _r.x : 0.0f;                                    \
    P_[0] = pkrtz(_eL, _q.x);                                                \
    P_[1] = pkrtz(_q.x, _q.y);                                               \
    P_[2] = pkrtz(_q.y, _q.z);                                               \
    P_[3] = pkrtz(_q.z, _q.w);                                               \
    P_[4] = pkrtz(_q.w, _eR);                                                \
} while (0)

#define LOADWIN(W_, r) do {                                                  \
    const int _o = (r) * WW;                                                 \
    LOADCVT(W_.d, dptr, _o); LOADCVT(W_.m, mptr, _o);                        \
    LOADCVT(W_.x, xptr, _o); LOADCVT(W_.y, yptr, _o);                        \
    LOADCVT(W_.z, zptr, _o);                                                 \
} while (0)

#define TAP(S_, pi, cD, cX, cY, cZ, WSC, A_) do {                            \
    const h2 _wd = wpoly(S_.d[pi] - (cD));                                   \
    const h2 _w0 = wpoly(S_.x[pi] - (cX));                                   \
    const h2 _w1 = wpoly(S_.y[pi] - (cY));                                   \
    const h2 _w2 = wpoly(S_.z[pi] - (cZ));                                   \
    const h2 _wc = _w0 + _w1 + _w2;                                          \
    const h2 _t  = (_wd * _wc) * (H2c(WSC) * S_.m[pi]);                      \
    A_.swd += _wd; A_.swc += _wc; A_.st += _t;                               \
    A_.s0 += _t * S_.x[pi]; A_.s1 += _t * S_.y[pi]; A_.s2 += _t * S_.z[pi];  \
} while (0)

#define ROWPASS(S_, cd0,cx0,cy0,cz0, cd1,cx1,cy1,cz1, A0_, A1_, WSM, WSS) do { \
    TAP(S_, 0, cd0, cx0, cy0, cz0, WSS, A0_);                                \
    TAP(S_, 1, cd0, cx0, cy0, cz0, WSM, A0_);                                \
    TAP(S_, 2, cd0, cx0, cy0, cz0, WSS, A0_);                                \
    TAP(S_, 2, cd1, cx1, cy1, cz1, WSS, A1_);                                \
    TAP(S_, 3, cd1, cx1, cy1, cz1, WSM, A1_);                                \
    TAP(S_, 4, cd1, cx1, cy1, cz1, WSS, A1_);                                \
} while (0)

    RW A, B;
    LOADWIN(A, rA);
    LOADWIN(B, rA + 1);

    // Center copies (let A/B windows die before side-row passes reuse regs).
    const h2 cad0 = A.d[1], cad1 = A.d[3];
    const h2 cax0 = A.x[1], cax1 = A.x[3];
    const h2 cay0 = A.y[1], cay1 = A.y[3];
    const h2 caz0 = A.z[1], caz1 = A.z[3];
    const h2 cbd0 = B.d[1], cbd1 = B.d[3];
    const h2 cbx0 = B.x[1], cbx1 = B.x[3];
    const h2 cby0 = B.y[1], cby1 = B.y[3];
    const h2 cbz0 = B.z[1], cbz1 = B.z[3];

    Acc aa0{}, aa1{}, ab0{}, ab1{};

    ROWPASS(A, cad0,cax0,cay0,caz0, cad1,cax1,cay1,caz1, aa0, aa1, WS0f, WS1f);
    ROWPASS(B, cbd0,cbx0,cby0,cbz0, cbd1,cbx1,cby1,cbz1, ab0, ab1, WS0f, WS1f);
    ROWPASS(B, cad0,cax0,cay0,caz0, cad1,cax1,cay1,caz1, aa0, aa1, WS1f, WS2f);
    ROWPASS(A, cbd0,cbx0,cby0,cbz0, cbd1,cbx1,cby1,cbz1, ab0, ab1, WS1f, WS2f);

    const bool hasUp = (hp > 0);      // wave-uniform
    const bool hasDn = (hp < 255);    // wave-uniform

    if (hasUp) {
        RW T;
        LOADWIN(T, rA - 1);
        ROWPASS(T, cad0,cax0,cay0,caz0, cad1,cax1,cay1,caz1, aa0, aa1, WS1f, WS2f);
    }
    if (hasDn) {
        RW T;
        LOADWIN(T, rA + 2);
        ROWPASS(T, cbd0,cbx0,cby0,cbz0, cbd1,cbx1,cby1,cbz1, ab0, ab1, WS1f, WS2f);
    }
    // (top/bottom skipped rows only affect the 9e-7 guard term; established)

    // fp32 epilogue: out = S / (St + 9e-7*Swd*Swc)
#define EPI(A_, o0, o1, o2, i0, i1) do {                                     \
    {                                                                        \
        const float st  = (float)A_.st[0];                                   \
        const float g   = st + 9e-7f * (float)A_.swd[0] * (float)A_.swc[0];  \
        const float inv = __builtin_amdgcn_rcpf(g);                          \
        o0[i0] = (float)A_.s0[0] * inv;                                      \
        o1[i0] = (float)A_.s1[0] * inv;                                      \
        o2[i0] = (float)A_.s2[0] * inv;                                      \
    }                                                                        \
    {                                                                        \
        const float st  = (float)A_.st[1];                                   \
        const float g   = st + 9e-7f * (float)A_.swd[1] * (float)A_.swc[1];  \
        const float inv = __builtin_amdgcn_rcpf(g);                          \
        o0[i1] = (float)A_.s0[1] * inv;                                      \
        o1[i1] = (float)A_.s1[1] * inv;                                      \
        o2[i1] = (float)A_.s2[1] * inv;                                      \
    }                                                                        \
} while (0)

    float ra0[4], ra1[4], ra2[4], rb0[4], rb1[4], rb2[4];
    EPI(aa0, ra0, ra1, ra2, 0, 1);
    EPI(aa1, ra0, ra1, ra2, 2, 3);
    EPI(ab0, rb0, rb1, rb2, 0, 1);
    EPI(ab1, rb0, rb1, rb2, 2, 3);

    float* po = out + (size_t)n * 3 * HW + rA * WW + c0;
    *reinterpret_cast<float4*>(po)               = make_float4(ra0[0], ra0[1], ra0[2], ra0[3]);
    *reinterpret_cast<float4*>(po + HW)          = make_float4(ra1[0], ra1[1], ra1[2], ra1[3]);
    *reinterpret_cast<float4*>(po + 2 * HW)      = make_float4(ra2[0], ra2[1], ra2[2], ra2[3]);
    *reinterpret_cast<float4*>(po + WW)          = make_float4(rb0[0], rb0[1], rb0[2], rb0[3]);
    *reinterpret_cast<float4*>(po + WW + HW)     = make_float4(rb1[0], rb1[1], rb1[2], rb1[3]);
    *reinterpret_cast<float4*>(po + WW + 2 * HW) = make_float4(rb2[0], rb2[1], rb2[2], rb2[3]);
}

extern "C" void kernel_launch(void* const* d_in, const int* in_sizes, int n_in,
                              void* d_out, int out_size, void* d_ws, size_t ws_size,
                              hipStream_t stream) {
    const float* depth = (const float*)d_in[0];
    const float* color = (const float*)d_in[1];
    const float* mask  = (const float*)d_in[2];
    float* out = (float*)d_out;

    // 8 images * 256 row-pairs * 2 halves = 4096 waves; 4 waves/block
    bilateral_v11<<<1024, 256, 0, stream>>>(depth, color, mask, out);
}